// Round 7
// baseline (2356.603 us; speedup 1.0000x reference)
//
#include <hip/hip_runtime.h>
#include <hip/hip_bf16.h>

typedef unsigned int uint;
typedef unsigned short u16;

#define D_ 4096
#define H_ 32
#define DH 128
#define F_ 8192
#define V_ 8192
#define S_ 1024
#define M_ 512
#define L_ 2
#define KV_ (M_ + S_)

typedef __attribute__((ext_vector_type(8))) short s16x8;
typedef __attribute__((ext_vector_type(4))) float f32x4;
typedef __attribute__((ext_vector_type(4))) u16 u16x4;

__device__ __forceinline__ u16 f2bf(float f) {
    uint u = __float_as_uint(f);
    u += 0x7FFFu + ((u >> 16) & 1u);
    return (u16)(u >> 16);
}
__device__ __forceinline__ float bf2f(u16 h) {
    return __uint_as_float(((uint)h) << 16);
}
__device__ __forceinline__ uint cvt_pk_bf16(float a, float b) {
    uint r;
    asm volatile("v_cvt_pk_bf16_f32 %0, %1, %2" : "=v"(r) : "v"(a), "v"(b));
    return r;
}
__device__ __forceinline__ void gload_lds16(const void* g, void* l) {
    __builtin_amdgcn_global_load_lds(
        (const __attribute__((address_space(1))) unsigned int*)g,
        (__attribute__((address_space(3))) unsigned int*)l, 16, 0, 0);
}

// ---------------- embedding gather ------------------------------------------
__global__ void k_embed(const int* __restrict__ ids, const float* __restrict__ embed,
                        float* __restrict__ h) {
    int row = blockIdx.x;
    const float4* src = (const float4*)(embed + (size_t)ids[row] * D_);
    float4* dst = (float4*)(h + (size_t)row * D_);
    for (int i = threadIdx.x; i < D_ / 4; i += 256) dst[i] = src[i];
}

// ---------------- RMSNorm ---------------------------------------------------
__global__ __launch_bounds__(256) void k_rms(const float* __restrict__ hin,
                                             const float* __restrict__ w,
                                             u16* __restrict__ out) {
    int row = blockIdx.x, t = threadIdx.x;
    const float4* src = (const float4*)(hin + (size_t)row * D_);
    float4 v[4];
    float ss = 0.f;
#pragma unroll
    for (int i = 0; i < 4; ++i) {
        v[i] = src[t + 256 * i];
        ss += v[i].x * v[i].x + v[i].y * v[i].y + v[i].z * v[i].z + v[i].w * v[i].w;
    }
#pragma unroll
    for (int off = 32; off; off >>= 1) ss += __shfl_xor(ss, off);
    __shared__ float red[4];
    if ((t & 63) == 0) red[t >> 6] = ss;
    __syncthreads();
    float tot = red[0] + red[1] + red[2] + red[3];
    float sc = rsqrtf(tot * (1.0f / D_) + 1e-5f);
    const float4* wp = (const float4*)w;
    u16x4* op = (u16x4*)(out + (size_t)row * D_);
#pragma unroll
    for (int i = 0; i < 4; ++i) {
        float4 wv = wp[t + 256 * i];
        u16x4 o;
        o[0] = f2bf(v[i].x * sc * wv.x);
        o[1] = f2bf(v[i].y * sc * wv.y);
        o[2] = f2bf(v[i].z * sc * wv.z);
        o[3] = f2bf(v[i].w * sc * wv.w);
        op[t + 256 * i] = o;
    }
}

// ---------------- f32 -> bf16 convert (memory slab only) --------------------
__global__ void k_cvt(const float* __restrict__ src, u16* __restrict__ dst, int n4) {
    int i = blockIdx.x * 256 + threadIdx.x;
    if (i < n4) {
        float4 v = ((const float4*)src)[i];
        u16x4 o;
        o[0] = f2bf(v.x); o[1] = f2bf(v.y); o[2] = f2bf(v.z); o[3] = f2bf(v.w);
        ((u16x4*)dst)[i] = o;
    }
}

// ---------------- silu(g)*u -> bf16 -----------------------------------------
__global__ void k_silu(const float* __restrict__ G, const float* __restrict__ U,
                       u16* __restrict__ out, int n4) {
    int i = blockIdx.x * 256 + threadIdx.x;
    if (i < n4) {
        float4 g = ((const float4*)G)[i];
        float4 u = ((const float4*)U)[i];
        u16x4 o;
        o[0] = f2bf(g.x / (1.0f + __expf(-g.x)) * u.x);
        o[1] = f2bf(g.y / (1.0f + __expf(-g.y)) * u.y);
        o[2] = f2bf(g.z / (1.0f + __expf(-g.z)) * u.z);
        o[3] = f2bf(g.w / (1.0f + __expf(-g.w)) * u.w);
        ((u16x4*)out)[i] = o;
    }
}

// ---------------- RoPE cos/sin table ----------------------------------------
__global__ void k_ropetab(float* __restrict__ tab) {
    int pos = blockIdx.x, i = threadIdx.x;  // 64 threads
    float invf = powf(10000.0f, -(float)i * (1.0f / 64.0f));
    float ang = (float)pos * invf;
    tab[(size_t)pos * 128 + i * 2] = cosf(ang);
    tab[(size_t)pos * 128 + i * 2 + 1] = sinf(ang);
}

// ---------------- RoPE in-place (table-driven) ------------------------------
__global__ __launch_bounds__(256) void k_rope(u16* __restrict__ buf,
                                              const float* __restrict__ tab, int pos0) {
    int row = blockIdx.x, t = threadIdx.x;
    const float2* tp = (const float2*)(tab + (size_t)(pos0 + row) * 128);
    u16* p = buf + (size_t)row * D_;
#pragma unroll
    for (int j = 0; j < 8; ++j) {
        int pid = t + 256 * j;
        int hd = pid >> 6, i = pid & 63;
        float2 cs = tp[i];
        int base = hd * 128 + i;
        float v0 = bf2f(p[base]), v1 = bf2f(p[base + 64]);
        p[base] = f2bf(v0 * cs.x - v1 * cs.y);
        p[base + 64] = f2bf(v1 * cs.x + v0 * cs.y);
    }
}

// ---------------- transpose Vb [KV][D] -> VT [D][KV] ------------------------
__global__ __launch_bounds__(256) void k_transpose(const u16* __restrict__ src,
                                                   u16* __restrict__ dst) {
    __shared__ u16 tile[64][66];
    int tc = blockIdx.x * 64;
    int tr = blockIdx.y * 64;
    int t = threadIdx.x;
    int c = t & 63, r0 = t >> 6;
#pragma unroll
    for (int i = 0; i < 16; ++i) {
        int r = r0 + i * 4;
        tile[r][c] = src[(size_t)(tr + r) * D_ + tc + c];
    }
    __syncthreads();
#pragma unroll
    for (int i = 0; i < 16; ++i) {
        int r = r0 + i * 4;
        dst[(size_t)(tc + r) * KV_ + tr + c] = tile[c][r];
    }
}

// ======================= 8-phase 256x256 GEMM ================================
// C[mrows x Nn] = A(bf16 [M][K]) @ B(f32 [N][K])^T per z-slice.
// Fragment-reuse schedule: per K-tile only 24 ds_read_b128/wave (the minimum):
// q0: af(qm0)+bb0   q1: bb1   q2: af(qm1)   q3: none — bb0/bb1 held in regs
// across the tile, af held across 2 phases. B f32 reg-staged (T14), cvt_pk,
// swizzled ds_write. A via gload_lds (pre-swizzled source). vmcnt(6)/tile.
struct GemmB8 {
    const u16* A[5];
    const float* B[5];
    void* O[5];
    int mrows[5];
};

template <int EPI>
__global__ __launch_bounds__(512, 2) void k_gemm8(GemmB8 P, int Nn, int Kfull) {
    int z = blockIdx.z;
    size_t bm = blockIdx.y, bn = blockIdx.x;
    if ((int)(bm * 256) >= P.mrows[z]) return;
    const u16* A = P.A[z];
    const float* Bw = P.B[z];
    __shared__ __align__(16) u16 AB[2][2][2][128][64];  // [buf][A/B][half][row][k]

    const int tid = threadIdx.x;
    const int lane = tid & 63, wid = tid >> 6;
    const int l16 = lane & 15, lh = lane >> 4;
    const int wrow = (wid >> 2) * 64;
    const int wcol = (wid & 3) * 32;
    const int nt = Kfull >> 6;

    // A staging map (gload_lds)
    const int grow0 = tid >> 3;
    const int gsw = ((tid & 7) ^ (grow0 & 7)) * 8;  // inverse-swizzled src group
    const u16* pA = A + (size_t)(bm * 256 + grow0) * Kfull + gsw;
    auto stageA = [&](int h, int t) {
        if (t >= nt) return;
        const u16* g = pA + (size_t)(h * 128) * Kfull + t * 64;
        u16* l = &AB[t & 1][0][h][0][0] + tid * 8;
        gload_lds16(g, l);
        gload_lds16(g + (size_t)64 * Kfull, l + 4096);
    };

    // B staging map (reg)
    const int brow = tid >> 3;
    const int bg = tid & 7;
    const float* pB = Bw + (size_t)(bn * 256 + brow) * Kfull + bg * 8;
    const int bwo = ((bg ^ (brow & 7)) * 8);
    auto loadB = [&](int h, int t, float4* br) {
        if (t >= nt) return;
        const float* g = pB + (size_t)(h * 128) * Kfull + t * 64;
        br[0] = *(const float4*)g;
        br[1] = *(const float4*)(g + 4);
        const float* g2 = g + (size_t)64 * Kfull;
        br[2] = *(const float4*)g2;
        br[3] = *(const float4*)(g2 + 4);
    };
    auto writeB = [&](int h, int t, const float4* br) {
        if (t >= nt) return;
        uint4 w0, w1;
        w0.x = cvt_pk_bf16(br[0].x, br[0].y); w0.y = cvt_pk_bf16(br[0].z, br[0].w);
        w0.z = cvt_pk_bf16(br[1].x, br[1].y); w0.w = cvt_pk_bf16(br[1].z, br[1].w);
        w1.x = cvt_pk_bf16(br[2].x, br[2].y); w1.y = cvt_pk_bf16(br[2].z, br[2].w);
        w1.z = cvt_pk_bf16(br[3].x, br[3].y); w1.w = cvt_pk_bf16(br[3].z, br[3].w);
        *(uint4*)(&AB[t & 1][1][h][brow][bwo]) = w0;
        *(uint4*)(&AB[t & 1][1][h][brow + 64][bwo]) = w1;
    };

    f32x4 acc[4][4][2];
#pragma unroll
    for (int q = 0; q < 4; ++q)
#pragma unroll
        for (int mf = 0; mf < 4; ++mf)
#pragma unroll
            for (int nf = 0; nf < 2; ++nf)
#pragma unroll
                for (int e = 0; e < 4; ++e) acc[q][mf][nf][e] = 0.f;

    float4 brE[4], brO[4];
    // ---- prologue: A{T0.A0,T0.A1,T1.A0}; B{T0.B0,T0.B1,T1.B0}; T1.B1 -> brO
    stageA(0, 0); stageA(1, 0); stageA(0, 1);
    {
        float4 b0[4], b1[4], b2[4];
        loadB(0, 0, b0); loadB(1, 0, b1); loadB(0, 1, b2);
        writeB(0, 0, b0); writeB(1, 0, b1); writeB(0, 1, b2);  // reg-dep drains A too
        loadB(1, 1, brO);
    }
    asm volatile("s_waitcnt lgkmcnt(0)" ::: "memory");
    __builtin_amdgcn_s_barrier();
    asm volatile("" ::: "memory");

    for (int T = 0; T < nt; ++T) {
        const int cb = T & 1;
        s16x8 af[4][2], bb0[2][2], bb1[2][2];

        // ======== q0: read af(qm=0)+bb0(qn=0); issue (T+2).B0 ========
#pragma unroll
        for (int kk = 0; kk < 2; ++kk) {
            const int sw = ((kk * 4 + lh) ^ (l16 & 7)) * 8;
#pragma unroll
            for (int mf = 0; mf < 4; ++mf)
                af[mf][kk] = *(const s16x8*)(&AB[cb][0][0][wrow + mf * 16 + l16][sw]);
#pragma unroll
            for (int nf = 0; nf < 2; ++nf)
                bb0[nf][kk] = *(const s16x8*)(&AB[cb][1][0][wcol + nf * 16 + l16][sw]);
        }
        loadB(0, T + 2, brE);
        asm volatile("" ::: "memory");
        __builtin_amdgcn_s_barrier();
        asm volatile("" ::: "memory");
        __builtin_amdgcn_s_setprio(1);
#pragma unroll
        for (int kk = 0; kk < 2; ++kk)
#pragma unroll
            for (int mf = 0; mf < 4; ++mf)
#pragma unroll
                for (int nf = 0; nf < 2; ++nf)
                    acc[0][mf][nf] = __builtin_amdgcn_mfma_f32_16x16x32_bf16(
                        af[mf][kk], bb0[nf][kk], acc[0][mf][nf], 0, 0, 0);
        __builtin_amdgcn_s_setprio(0);
        asm volatile("" ::: "memory");
        __builtin_amdgcn_s_barrier();
        asm volatile("" ::: "memory");

        // ======== q1: read bb1(qn=1); land (T+1).B1 + stage (T+1).A1 ========
#pragma unroll
        for (int kk = 0; kk < 2; ++kk) {
            const int sw = ((kk * 4 + lh) ^ (l16 & 7)) * 8;
#pragma unroll
            for (int nf = 0; nf < 2; ++nf)
                bb1[nf][kk] = *(const s16x8*)(&AB[cb][1][1][wcol + nf * 16 + l16][sw]);
        }
        writeB(1, T + 1, brO);
        stageA(1, T + 1);
        asm volatile("s_waitcnt lgkmcnt(0)" ::: "memory");
        __builtin_amdgcn_s_barrier();
        asm volatile("" ::: "memory");
        __builtin_amdgcn_s_setprio(1);
#pragma unroll
        for (int kk = 0; kk < 2; ++kk)
#pragma unroll
            for (int mf = 0; mf < 4; ++mf)
#pragma unroll
                for (int nf = 0; nf < 2; ++nf)
                    acc[1][mf][nf] = __builtin_amdgcn_mfma_f32_16x16x32_bf16(
                        af[mf][kk], bb1[nf][kk], acc[1][mf][nf], 0, 0, 0);
        __builtin_amdgcn_s_setprio(0);
        asm volatile("" ::: "memory");
        __builtin_amdgcn_s_barrier();
        asm volatile("" ::: "memory");

        // ======== q2: read af(qm=1); issue (T+2).B1 ========
#pragma unroll
        for (int kk = 0; kk < 2; ++kk) {
            const int sw = ((kk * 4 + lh) ^ (l16 & 7)) * 8;
#pragma unroll
            for (int mf = 0; mf < 4; ++mf)
                af[mf][kk] = *(const s16x8*)(&AB[cb][0][1][wrow + mf * 16 + l16][sw]);
        }
        loadB(1, T + 2, brO);
        asm volatile("" ::: "memory");
        __builtin_amdgcn_s_barrier();
        asm volatile("" ::: "memory");
        __builtin_amdgcn_s_setprio(1);
#pragma unroll
        for (int kk = 0; kk < 2; ++kk)
#pragma unroll
            for (int mf = 0; mf < 4; ++mf)
#pragma unroll
                for (int nf = 0; nf < 2; ++nf)
                    acc[2][mf][nf] = __builtin_amdgcn_mfma_f32_16x16x32_bf16(
                        af[mf][kk], bb0[nf][kk], acc[2][mf][nf], 0, 0, 0);
        __builtin_amdgcn_s_setprio(0);
        asm volatile("" ::: "memory");
        __builtin_amdgcn_s_barrier();
        asm volatile("" ::: "memory");

        // ======== q3: land (T+2).B0 + stage (T+2).A0; vmcnt ========
        writeB(0, T + 2, brE);
        stageA(0, T + 2);
        asm volatile("s_waitcnt lgkmcnt(0)" ::: "memory");
        __builtin_amdgcn_s_barrier();
        asm volatile("" ::: "memory");
        __builtin_amdgcn_s_setprio(1);
#pragma unroll
        for (int kk = 0; kk < 2; ++kk)
#pragma unroll
            for (int mf = 0; mf < 4; ++mf)
#pragma unroll
                for (int nf = 0; nf < 2; ++nf)
                    acc[3][mf][nf] = __builtin_amdgcn_mfma_f32_16x16x32_bf16(
                        af[mf][kk], bb1[nf][kk], acc[3][mf][nf], 0, 0, 0);
        __builtin_amdgcn_s_setprio(0);
        if (T < nt - 3) asm volatile("s_waitcnt vmcnt(6)" ::: "memory");
        else asm volatile("s_waitcnt vmcnt(0)" ::: "memory");
        asm volatile("" ::: "memory");
        __builtin_amdgcn_s_barrier();
        asm volatile("" ::: "memory");
    }

    void* Oo = P.O[z];
#pragma unroll
    for (int q = 0; q < 4; ++q) {
        const int qm = q >> 1, qn = q & 1;
#pragma unroll
        for (int mf = 0; mf < 4; ++mf) {
#pragma unroll
            for (int nf = 0; nf < 2; ++nf) {
#pragma unroll
                for (int rr = 0; rr < 4; ++rr) {
                    int grow = (int)bm * 256 + qm * 128 + wrow + mf * 16 + lh * 4 + rr;
                    int gcol = (int)bn * 256 + qn * 128 + wcol + nf * 16 + l16;
                    size_t idx = (size_t)grow * Nn + gcol;
                    float v = acc[q][mf][nf][rr];
                    if constexpr (EPI == 0) ((u16*)Oo)[idx] = f2bf(v);
                    else ((float*)Oo)[idx] = v;
                }
            }
        }
    }
}

// ======================= 2-phase 128x128 GEMM (f32 B, reg-staged) ============
struct GemmB2 {
    const u16* A[5];
    const float* B[5];
    void* O[5];
    int mrows[5];
};

template <int EPI>
__global__ __launch_bounds__(256) void k_gemm2(GemmB2 P, int Nn, int Kfull) {
    int z = blockIdx.z;
    size_t bm = blockIdx.y, bn = blockIdx.x;
    if ((int)(bm * 128) >= P.mrows[z]) return;
    const u16* A = P.A[z];
    const float* Bw = P.B[z];
    __shared__ __align__(16) u16 As[128 * 64];
    __shared__ __align__(16) u16 Bs[128 * 64];
    int tid = threadIdx.x;
    int lane = tid & 63, wid = tid >> 6;
    int l16 = lane & 15, lh = lane >> 4;
    int wm = (wid >> 1) * 64, wn = (wid & 1) * 64;

    const u16* pA[4];
    const float* pB[4];
    int ldso[4], bso[4];
#pragma unroll
    for (int i = 0; i < 4; ++i) {
        int c = tid + 256 * i;
        int r = c >> 3, s = c & 7;
        pA[i] = A + (size_t)(bm * 128 + r) * Kfull + ((s ^ (r & 7)) * 8);
        pB[i] = Bw + (size_t)(bn * 128 + r) * Kfull + s * 8;
        ldso[i] = c * 8;
        bso[i] = r * 64 + ((s ^ (r & 7)) * 8);
    }

    f32x4 acc[4][4];
#pragma unroll
    for (int i = 0; i < 4; ++i)
#pragma unroll
        for (int j = 0; j < 4; ++j)
#pragma unroll
            for (int e = 0; e < 4; ++e) acc[i][j][e] = 0.f;

    float4 br[8];
    auto loadB = [&](int k0) {
#pragma unroll
        for (int i = 0; i < 4; ++i) {
            br[2 * i] = *(const float4*)(pB[i] + k0);
            br[2 * i + 1] = *(const float4*)(pB[i] + k0 + 4);
        }
    };
    auto cvtwriteB = [&]() {
#pragma unroll
        for (int i = 0; i < 4; ++i) {
            uint4 w;
            w.x = cvt_pk_bf16(br[2 * i].x, br[2 * i].y);
            w.y = cvt_pk_bf16(br[2 * i].z, br[2 * i].w);
            w.z = cvt_pk_bf16(br[2 * i + 1].x, br[2 * i + 1].y);
            w.w = cvt_pk_bf16(br[2 * i + 1].z, br[2 * i + 1].w);
            *(uint4*)(&Bs[bso[i]]) = w;
        }
    };

    int nt = Kfull >> 6;
    loadB(0);
    for (int t = 0; t < nt; ++t) {
#pragma unroll
        for (int i = 0; i < 4; ++i) gload_lds16(pA[i] + (t << 6), &As[ldso[i]]);
        cvtwriteB();
        if (t + 1 < nt) loadB((t + 1) << 6);
        asm volatile("s_waitcnt vmcnt(8) lgkmcnt(0)" ::: "memory");
        __syncthreads();
#pragma unroll
        for (int kk = 0; kk < 2; ++kk) {
            int sidx = kk * 4 + lh;
            int sw = (sidx ^ (l16 & 7)) * 8;
            s16x8 af[4], bf4[4];
#pragma unroll
            for (int mi = 0; mi < 4; ++mi)
                af[mi] = *(const s16x8*)(&As[(wm + mi * 16 + l16) * 64 + sw]);
#pragma unroll
            for (int ni = 0; ni < 4; ++ni)
                bf4[ni] = *(const s16x8*)(&Bs[(wn + ni * 16 + l16) * 64 + sw]);
#pragma unroll
            for (int mi = 0; mi < 4; ++mi)
#pragma unroll
                for (int ni = 0; ni < 4; ++ni)
                    acc[mi][ni] = __builtin_amdgcn_mfma_f32_16x16x32_bf16(
                        af[mi], bf4[ni], acc[mi][ni], 0, 0, 0);
        }
        __syncthreads();
    }

    void* Oo = P.O[z];
#pragma unroll
    for (int mi = 0; mi < 4; ++mi) {
#pragma unroll
        for (int ni = 0; ni < 4; ++ni) {
#pragma unroll
            for (int r = 0; r < 4; ++r) {
                int grow = (int)bm * 128 + wm + mi * 16 + lh * 4 + r;
                int gcol = (int)bn * 128 + wn + ni * 16 + l16;
                size_t idx = (size_t)grow * Nn + gcol;
                float v = acc[mi][ni][r];
                if constexpr (EPI == 1) ((float*)Oo)[idx] = v;
                else ((float*)Oo)[idx] += v;
            }
        }
    }
}

// ---------------- flash attention: 1 wave per (16 q-rows, head) -------------
__global__ __launch_bounds__(64) void k_attn(const u16* __restrict__ Qb,
                                             const u16* __restrict__ Kb,
                                             const u16* __restrict__ VT,
                                             u16* __restrict__ Ob) {
    int qt = blockIdx.x, hd = blockIdx.y;
    int lane = threadIdx.x, l16 = lane & 15, lh = lane >> 4;
    __shared__ __align__(16) float Pl[16 * 36];

    s16x8 qf[4];
#pragma unroll
    for (int c = 0; c < 4; ++c)
        qf[c] = *(const s16x8*)(Qb + (size_t)(qt * 16 + l16) * D_ + hd * DH + c * 32 + lh * 8);

    f32x4 o[8];
#pragma unroll
    for (int dc = 0; dc < 8; ++dc)
#pragma unroll
        for (int e = 0; e < 4; ++e) o[dc][e] = 0.f;
    float m[4], lsum[4];
#pragma unroll
    for (int r = 0; r < 4; ++r) { m[r] = -1e30f; lsum[r] = 0.f; }

    const float scale = 0.08838834764831845f;
    int qbase = M_ + qt * 16;
    int nkb = (M_ + qt * 16 + 16 + 31) >> 5;

    for (int kb = 0; kb < nkb; ++kb) {
        f32x4 s0, s1;
#pragma unroll
        for (int e = 0; e < 4; ++e) { s0[e] = 0.f; s1[e] = 0.f; }
#pragma unroll
        for (int c = 0; c < 4; ++c) {
            s16x8 kf0 = *(const s16x8*)(Kb + (size_t)(kb * 32 + l16) * D_ + hd * DH + c * 32 + lh * 8);
            s16x8 kf1 = *(const s16x8*)(Kb + (size_t)(kb * 32 + 16 + l16) * D_ + hd * DH + c * 32 + lh * 8);
            s0 = __builtin_amdgcn_mfma_f32_16x16x32_bf16(qf[c], kf0, s0, 0, 0, 0);
            s1 = __builtin_amdgcn_mfma_f32_16x16x32_bf16(qf[c], kf1, s1, 0, 0, 0);
        }
        int kp0 = kb * 32 + l16, kp1 = kp0 + 16;
        float pm[4];
#pragma unroll
        for (int r = 0; r < 4; ++r) {
            int qp = qbase + lh * 4 + r;
            float v0 = s0[r] * scale; if (kp0 > qp) v0 = -1e30f;
            float v1 = s1[r] * scale; if (kp1 > qp) v1 = -1e30f;
            s0[r] = v0; s1[r] = v1;
            pm[r] = fmaxf(v0, v1);
        }
#pragma unroll
        for (int r = 0; r < 4; ++r) {
#pragma unroll
            for (int off = 8; off; off >>= 1) pm[r] = fmaxf(pm[r], __shfl_xor(pm[r], off));
        }
        float alpha[4];
#pragma unroll
        for (int r = 0; r < 4; ++r) {
            float mn = fmaxf(m[r], pm[r]);
            alpha[r] = __expf(m[r] - mn);
            m[r] = mn;
            float p0 = __expf(s0[r] - mn), p1 = __expf(s1[r] - mn);
            s0[r] = p0; s1[r] = p1;
            float t = p0 + p1;
#pragma unroll
            for (int off = 8; off; off >>= 1) t += __shfl_xor(t, off);
            lsum[r] = lsum[r] * alpha[r] + t;
        }
#pragma unroll
        for (int r = 0; r < 4; ++r) {
            Pl[(lh * 4 + r) * 36 + l16] = s0[r];
            Pl[(lh * 4 + r) * 36 + 16 + l16] = s1[r];
        }
        __syncthreads();
        s16x8 pf;
        {
            const f32x4* pp = (const f32x4*)(Pl + l16 * 36 + lh * 8);
            f32x4 a = pp[0], b = pp[1];
            pf[0] = (short)f2bf(a[0]); pf[1] = (short)f2bf(a[1]);
            pf[2] = (short)f2bf(a[2]); pf[3] = (short)f2bf(a[3]);
            pf[4] = (short)f2bf(b[0]); pf[5] = (short)f2bf(b[1]);
            pf[6] = (short)f2bf(b[2]); pf[7] = (short)f2bf(b[3]);
        }
        __syncthreads();
#pragma unroll
        for (int dc = 0; dc < 8; ++dc) {
#pragma unroll
            for (int r = 0; r < 4; ++r) o[dc][r] *= alpha[r];
        }
#pragma unroll
        for (int dc = 0; dc < 8; ++dc) {
            s16x8 vf = *(const s16x8*)(VT + (size_t)(hd * DH + dc * 16 + l16) * KV_ + kb * 32 + lh * 8);
            o[dc] = __builtin_amdgcn_mfma_f32_16x16x32_bf16(pf, vf, o[dc], 0, 0, 0);
        }
    }
#pragma unroll
    for (int dc = 0; dc < 8; ++dc) {
#pragma unroll
        for (int r = 0; r < 4; ++r) {
            float val = o[dc][r] / lsum[r];
            Ob[(size_t)(qt * 16 + lh * 4 + r) * D_ + hd * DH + dc * 16 + l16] = f2bf(val);
        }
    }
}

// ---------------- launch ----------------------------------------------------
extern "C" void kernel_launch(void* const* d_in, const int* in_sizes, int n_in,
                              void* d_out, int out_size, void* d_ws, size_t ws_size,
                              hipStream_t stream) {
    const int* ids = (const int*)d_in[0];
    const float* memory = (const float*)d_in[1];
    const float* embed = (const float*)d_in[2];
    const float* Wq = (const float*)d_in[3];
    const float* Wk = (const float*)d_in[4];
    const float* Wv = (const float*)d_in[5];
    const float* Wo = (const float*)d_in[6];
    const float* Wg = (const float*)d_in[7];
    const float* Wu = (const float*)d_in[8];
    const float* Wd = (const float*)d_in[9];
    const float* Wmk = (const float*)d_in[10];
    const float* Wmv = (const float*)d_in[11];
    const float* ln1 = (const float*)d_in[12];
    const float* ln2 = (const float*)d_in[13];
    const float* normw = (const float*)d_in[14];
    const float* lm = (const float*)d_in[15];

    char* ws = (char*)d_ws;
    float* h   = (float*)(ws + 0x0000000);   // 16.78 MB f32 [S][D]
    u16* xb    = (u16*)(ws + 0x1000000);     // 8.39 MB bf16 [S][D]
    float* tab = (float*)(ws + 0x1800000);   // 0.79 MB
    u16* memb  = (u16*)(ws + 0x1900000);     // 4.19 MB
    u16* Qb    = (u16*)(ws + 0x1E00000);     // 8.39 MB
    u16* Kb    = (u16*)(ws + 0x2600000);     // 12.58 MB [KV][D]
    u16* Vb    = (u16*)(ws + 0x3200000);     // 12.58 MB
    u16* VT    = (u16*)(ws + 0x3E00000);     // 12.58 MB [D][KV]
    u16* Ob    = (u16*)(ws + 0x4A00000);     // 8.39 MB
    // FFN overlays (Qb..Ob dead then):
    float* Gbuf = (float*)(ws + 0x1E00000);  // 33.55 MB f32 [S][F]
    u16* tb     = (u16*)(ws + 0x3E00000);    // 16.78 MB bf16 [S][F]
    float* Ubuf = (float*)(ws + 0x4E00000);  // 33.55 MB f32 [S][F] -> end 0x6E00000

    k_embed<<<S_, 256, 0, stream>>>(ids, embed, h);
    k_ropetab<<<KV_, 64, 0, stream>>>(tab);

    for (int l = 0; l < L_; ++l) {
        const size_t oDD = (size_t)l * D_ * D_;
        const size_t oFD = (size_t)l * F_ * D_;

        k_rms<<<S_, 256, 0, stream>>>(h, ln1 + l * D_, xb);
        k_cvt<<<(M_ * D_ / 4 + 255) / 256, 256, 0, stream>>>(
            memory + (size_t)l * M_ * D_, memb, M_ * D_ / 4);

        // QKV + memory-KV: 8-phase 256^2, 5 z-slices
        GemmB8 g1{};
        g1.A[0] = xb;   g1.B[0] = Wq + oDD;  g1.O[0] = Qb;                    g1.mrows[0] = S_;
        g1.A[1] = xb;   g1.B[1] = Wk + oDD;  g1.O[1] = Kb + (size_t)M_ * D_;  g1.mrows[1] = S_;
        g1.A[2] = xb;   g1.B[2] = Wv + oDD;  g1.O[2] = Vb + (size_t)M_ * D_;  g1.mrows[2] = S_;
        g1.A[3] = memb; g1.B[3] = Wmk + oDD; g1.O[3] = Kb;                    g1.mrows[3] = M_;
        g1.A[4] = memb; g1.B[4] = Wmv + oDD; g1.O[4] = Vb;                    g1.mrows[4] = M_;
        k_gemm8<0><<<dim3(D_ / 256, S_ / 256, 5), 512, 0, stream>>>(g1, D_, D_);

        k_rope<<<S_, 256, 0, stream>>>(Qb, tab, M_);
        k_rope<<<KV_, 256, 0, stream>>>(Kb, tab, 0);
        k_transpose<<<dim3(D_ / 64, KV_ / 64), 256, 0, stream>>>(Vb, VT);
        k_attn<<<dim3(S_ / 16, H_), 64, 0, stream>>>(Qb, Kb, VT, Ob);

        // h += Ob @ Wo^T
        GemmB2 g2{};
        g2.A[0] = Ob; g2.B[0] = Wo + oDD; g2.O[0] = h; g2.mrows[0] = S_;
        k_gemm2<2><<<dim3(D_ / 128, S_ / 128, 1), 256, 0, stream>>>(g2, D_, D_);

        // FFN
        k_rms<<<S_, 256, 0, stream>>>(h, ln2 + l * D_, xb);
        GemmB8 g3{};
        g3.A[0] = xb; g3.B[0] = Wg + oFD; g3.O[0] = Gbuf; g3.mrows[0] = S_;
        g3.A[1] = xb; g3.B[1] = Wu + oFD; g3.O[1] = Ubuf; g3.mrows[1] = S_;
        k_gemm8<1><<<dim3(F_ / 256, S_ / 256, 2), 512, 0, stream>>>(g3, F_, D_);
        k_silu<<<(S_ * F_ / 4 + 255) / 256, 256, 0, stream>>>(Gbuf, Ubuf, tb, S_ * F_ / 4);
        GemmB2 g5{};
        g5.A[0] = tb; g5.B[0] = Wd + oFD; g5.O[0] = h; g5.mrows[0] = S_;
        k_gemm2<2><<<dim3(D_ / 128, S_ / 128, 1), 256, 0, stream>>>(g5, D_, F_);
    }

    k_rms<<<S_, 256, 0, stream>>>(h, normw, xb);
    GemmB2 g6{};
    g6.A[0] = xb; g6.B[0] = lm; g6.O[0] = (float*)d_out; g6.mrows[0] = S_;
    k_gemm2<1><<<dim3(V_ / 128, S_ / 128, 1), 256, 0, stream>>>(g6, V_, D_);
}

// Round 8
// 1885.112 us; speedup vs baseline: 1.2501x; 1.2501x over previous
//
#include <hip/hip_runtime.h>
#include <hip/hip_bf16.h>

typedef unsigned int uint;
typedef unsigned short u16;

#define D_ 4096
#define H_ 32
#define DH 128
#define F_ 8192
#define V_ 8192
#define S_ 1024
#define M_ 512
#define L_ 2
#define KV_ (M_ + S_)

typedef __attribute__((ext_vector_type(8))) short s16x8;
typedef __attribute__((ext_vector_type(4))) float f32x4;
typedef __attribute__((ext_vector_type(4))) u16 u16x4;

__device__ __forceinline__ u16 f2bf(float f) {
    uint u = __float_as_uint(f);
    u += 0x7FFFu + ((u >> 16) & 1u);
    return (u16)(u >> 16);
}
__device__ __forceinline__ float bf2f(u16 h) {
    return __uint_as_float(((uint)h) << 16);
}
__device__ __forceinline__ void gload_lds16(const void* g, void* l) {
    __builtin_amdgcn_global_load_lds(
        (const __attribute__((address_space(1))) unsigned int*)g,
        (__attribute__((address_space(3))) unsigned int*)l, 16, 0, 0);
}

// ---------------- embedding gather ------------------------------------------
__global__ void k_embed(const int* __restrict__ ids, const float* __restrict__ embed,
                        float* __restrict__ h) {
    int row = blockIdx.x;
    const float4* src = (const float4*)(embed + (size_t)ids[row] * D_);
    float4* dst = (float4*)(h + (size_t)row * D_);
    for (int i = threadIdx.x; i < D_ / 4; i += 256) dst[i] = src[i];
}

// ---------------- RMSNorm ---------------------------------------------------
__global__ __launch_bounds__(256) void k_rms(const float* __restrict__ hin,
                                             const float* __restrict__ w,
                                             u16* __restrict__ out) {
    int row = blockIdx.x, t = threadIdx.x;
    const float4* src = (const float4*)(hin + (size_t)row * D_);
    float4 v[4];
    float ss = 0.f;
#pragma unroll
    for (int i = 0; i < 4; ++i) {
        v[i] = src[t + 256 * i];
        ss += v[i].x * v[i].x + v[i].y * v[i].y + v[i].z * v[i].z + v[i].w * v[i].w;
    }
#pragma unroll
    for (int off = 32; off; off >>= 1) ss += __shfl_xor(ss, off);
    __shared__ float red[4];
    if ((t & 63) == 0) red[t >> 6] = ss;
    __syncthreads();
    float tot = red[0] + red[1] + red[2] + red[3];
    float sc = rsqrtf(tot * (1.0f / D_) + 1e-5f);
    const float4* wp = (const float4*)w;
    u16x4* op = (u16x4*)(out + (size_t)row * D_);
#pragma unroll
    for (int i = 0; i < 4; ++i) {
        float4 wv = wp[t + 256 * i];
        u16x4 o;
        o[0] = f2bf(v[i].x * sc * wv.x);
        o[1] = f2bf(v[i].y * sc * wv.y);
        o[2] = f2bf(v[i].z * sc * wv.z);
        o[3] = f2bf(v[i].w * sc * wv.w);
        op[t + 256 * i] = o;
    }
}

// ---------------- f32 -> bf16 convert ---------------------------------------
__global__ void k_cvt(const float* __restrict__ src, u16* __restrict__ dst, int n4) {
    int i = blockIdx.x * 256 + threadIdx.x;
    if (i < n4) {
        float4 v = ((const float4*)src)[i];
        u16x4 o;
        o[0] = f2bf(v.x); o[1] = f2bf(v.y); o[2] = f2bf(v.z); o[3] = f2bf(v.w);
        ((u16x4*)dst)[i] = o;
    }
}

// ---------------- silu(g)*u (bf16 in/out) -----------------------------------
__global__ void k_silu(const u16* __restrict__ G, const u16* __restrict__ U,
                       u16* __restrict__ out, int n8) {
    int i = blockIdx.x * 256 + threadIdx.x;
    if (i < n8) {
        s16x8 g = ((const s16x8*)G)[i];
        s16x8 u = ((const s16x8*)U)[i];
        s16x8 o;
#pragma unroll
        for (int j = 0; j < 8; ++j) {
            float gv = bf2f((u16)g[j]), uv = bf2f((u16)u[j]);
            o[j] = (short)f2bf(gv / (1.0f + __expf(-gv)) * uv);
        }
        ((s16x8*)out)[i] = o;
    }
}

// ---------------- RoPE cos/sin table ----------------------------------------
__global__ void k_ropetab(float* __restrict__ tab) {
    int pos = blockIdx.x, i = threadIdx.x;  // 64 threads
    float invf = powf(10000.0f, -(float)i * (1.0f / 64.0f));
    float ang = (float)pos * invf;
    tab[(size_t)pos * 128 + i * 2] = cosf(ang);
    tab[(size_t)pos * 128 + i * 2 + 1] = sinf(ang);
}

// ---------------- RoPE in-place (table-driven) ------------------------------
__global__ __launch_bounds__(256) void k_rope(u16* __restrict__ buf,
                                              const float* __restrict__ tab, int pos0) {
    int row = blockIdx.x, t = threadIdx.x;
    const float2* tp = (const float2*)(tab + (size_t)(pos0 + row) * 128);
    u16* p = buf + (size_t)row * D_;
#pragma unroll
    for (int j = 0; j < 8; ++j) {
        int pid = t + 256 * j;
        int hd = pid >> 6, i = pid & 63;
        float2 cs = tp[i];
        int base = hd * 128 + i;
        float v0 = bf2f(p[base]), v1 = bf2f(p[base + 64]);
        p[base] = f2bf(v0 * cs.x - v1 * cs.y);
        p[base + 64] = f2bf(v1 * cs.x + v0 * cs.y);
    }
}

// ---------------- transpose Vb [KV][D] -> VT [D][KV] ------------------------
__global__ __launch_bounds__(256) void k_transpose(const u16* __restrict__ src,
                                                   u16* __restrict__ dst) {
    __shared__ u16 tile[64][66];
    int tc = blockIdx.x * 64;
    int tr = blockIdx.y * 64;
    int t = threadIdx.x;
    int c = t & 63, r0 = t >> 6;
#pragma unroll
    for (int i = 0; i < 16; ++i) {
        int r = r0 + i * 4;
        tile[r][c] = src[(size_t)(tr + r) * D_ + tc + c];
    }
    __syncthreads();
#pragma unroll
    for (int i = 0; i < 16; ++i) {
        int r = r0 + i * 4;
        dst[(size_t)(tc + r) * KV_ + tr + c] = tile[c][r];
    }
}

// ======================= 8-phase 256x256 GEMM (bf16 both sides) ==============
// C[mrows x Nn] = A(bf16 [M][K]) @ B(bf16 [N][K])^T per z-slice.
// T2 swizzle (pre-swizzled global src, linear gload_lds dest, swizzled reads).
// af-hold read schedule: q0{af(qm0)+bb}, q1{bb only}, q2{af(qm1)+bb},
// q3{bb only} = 32 ds_read_b128/tile (vs 48). Counted vmcnt(4)/tile (T3+T4),
// setprio around MFMA (T5).
struct GemmB8 {
    const u16* A[5];
    const u16* B[5];
    void* O[5];
    int mrows[5];
};

template <int EPI>
__global__ __launch_bounds__(512, 2) void k_gemm8(GemmB8 P, int Nn, int Kfull) {
    int z = blockIdx.z;
    size_t bm = blockIdx.y, bn = blockIdx.x;
    if ((int)(bm * 256) >= P.mrows[z]) return;
    const u16* A = P.A[z];
    const u16* Bw = P.B[z];
    __shared__ __align__(16) u16 AB[2][2][2][128][64];  // [buf][A/B][half][row][k]

    const int tid = threadIdx.x;
    const int lane = tid & 63, wid = tid >> 6;
    const int l16 = lane & 15, lh = lane >> 4;
    const int wrow = (wid >> 2) * 64;
    const int wcol = (wid & 3) * 32;
    const int nt = Kfull >> 6;

    const int grow0 = tid >> 3;
    const int gsw = ((tid & 7) ^ (grow0 & 7)) * 8;  // inverse-swizzled src group
    const u16* pA = A + (size_t)(bm * 256 + grow0) * Kfull + gsw;
    const u16* pB = Bw + (size_t)(bn * 256 + grow0) * Kfull + gsw;

    auto stage = [&](const u16* base, int mat, int h, int t) {
        if (t >= nt) return;
        const u16* g = base + (size_t)(h * 128) * Kfull + t * 64;
        u16* l = &AB[t & 1][mat][h][0][0] + tid * 8;  // linear dest
        gload_lds16(g, l);
        gload_lds16(g + (size_t)64 * Kfull, l + 4096);
    };

    f32x4 acc[4][4][2];
#pragma unroll
    for (int q = 0; q < 4; ++q)
#pragma unroll
        for (int mf = 0; mf < 4; ++mf)
#pragma unroll
            for (int nf = 0; nf < 2; ++nf)
#pragma unroll
                for (int e = 0; e < 4; ++e) acc[q][mf][nf][e] = 0.f;

    // prologue: T0.{A0,B0,A1,B1}, T1.{A0,B0}
    stage(pA, 0, 0, 0); stage(pB, 1, 0, 0);
    stage(pA, 0, 1, 0); stage(pB, 1, 1, 0);
    stage(pA, 0, 0, 1); stage(pB, 1, 0, 1);
    asm volatile("s_waitcnt vmcnt(4)" ::: "memory");  // T0 fully landed
    __builtin_amdgcn_s_barrier();
    asm volatile("" ::: "memory");

    for (int T = 0; T < nt; ++T) {
        const int cb = T & 1;
        s16x8 af[4][2], bb[2][2];

        // -------- q0: read af(qm=0)+bb(qn=0); stage (T+1).A1 --------
#pragma unroll
        for (int kk = 0; kk < 2; ++kk) {
            const int sw = ((kk * 4 + lh) ^ (l16 & 7)) * 8;
#pragma unroll
            for (int mf = 0; mf < 4; ++mf)
                af[mf][kk] = *(const s16x8*)(&AB[cb][0][0][wrow + mf * 16 + l16][sw]);
#pragma unroll
            for (int nf = 0; nf < 2; ++nf)
                bb[nf][kk] = *(const s16x8*)(&AB[cb][1][0][wcol + nf * 16 + l16][sw]);
        }
        stage(pA, 0, 1, T + 1);
        asm volatile("" ::: "memory");
        __builtin_amdgcn_s_barrier();
        asm volatile("" ::: "memory");
        __builtin_amdgcn_s_setprio(1);
#pragma unroll
        for (int kk = 0; kk < 2; ++kk)
#pragma unroll
            for (int mf = 0; mf < 4; ++mf)
#pragma unroll
                for (int nf = 0; nf < 2; ++nf)
                    acc[0][mf][nf] = __builtin_amdgcn_mfma_f32_16x16x32_bf16(
                        af[mf][kk], bb[nf][kk], acc[0][mf][nf], 0, 0, 0);
        __builtin_amdgcn_s_setprio(0);
        asm volatile("" ::: "memory");
        __builtin_amdgcn_s_barrier();
        asm volatile("" ::: "memory");

        // -------- q1: read bb(qn=1) only (af held); stage (T+1).B1 --------
#pragma unroll
        for (int kk = 0; kk < 2; ++kk) {
            const int sw = ((kk * 4 + lh) ^ (l16 & 7)) * 8;
#pragma unroll
            for (int nf = 0; nf < 2; ++nf)
                bb[nf][kk] = *(const s16x8*)(&AB[cb][1][1][wcol + nf * 16 + l16][sw]);
        }
        stage(pB, 1, 1, T + 1);
        asm volatile("" ::: "memory");
        __builtin_amdgcn_s_barrier();
        asm volatile("" ::: "memory");
        __builtin_amdgcn_s_setprio(1);
#pragma unroll
        for (int kk = 0; kk < 2; ++kk)
#pragma unroll
            for (int mf = 0; mf < 4; ++mf)
#pragma unroll
                for (int nf = 0; nf < 2; ++nf)
                    acc[1][mf][nf] = __builtin_amdgcn_mfma_f32_16x16x32_bf16(
                        af[mf][kk], bb[nf][kk], acc[1][mf][nf], 0, 0, 0);
        __builtin_amdgcn_s_setprio(0);
        asm volatile("" ::: "memory");
        __builtin_amdgcn_s_barrier();
        asm volatile("" ::: "memory");

        // -------- q2: read af(qm=1)+bb(qn=0); stage (T+2).A0 --------
#pragma unroll
        for (int kk = 0; kk < 2; ++kk) {
            const int sw = ((kk * 4 + lh) ^ (l16 & 7)) * 8;
#pragma unroll
            for (int mf = 0; mf < 4; ++mf)
                af[mf][kk] = *(const s16x8*)(&AB[cb][0][1][wrow + mf * 16 + l16][sw]);
#pragma unroll
            for (int nf = 0; nf < 2; ++nf)
                bb[nf][kk] = *(const s16x8*)(&AB[cb][1][0][wcol + nf * 16 + l16][sw]);
        }
        stage(pA, 0, 0, T + 2);
        asm volatile("" ::: "memory");
        __builtin_amdgcn_s_barrier();
        asm volatile("" ::: "memory");
        __builtin_amdgcn_s_setprio(1);
#pragma unroll
        for (int kk = 0; kk < 2; ++kk)
#pragma unroll
            for (int mf = 0; mf < 4; ++mf)
#pragma unroll
                for (int nf = 0; nf < 2; ++nf)
                    acc[2][mf][nf] = __builtin_amdgcn_mfma_f32_16x16x32_bf16(
                        af[mf][kk], bb[nf][kk], acc[2][mf][nf], 0, 0, 0);
        __builtin_amdgcn_s_setprio(0);
        asm volatile("" ::: "memory");
        __builtin_amdgcn_s_barrier();
        asm volatile("" ::: "memory");

        // -------- q3: read bb(qn=1) only (af held); stage (T+2).B0; vmcnt ----
#pragma unroll
        for (int kk = 0; kk < 2; ++kk) {
            const int sw = ((kk * 4 + lh) ^ (l16 & 7)) * 8;
#pragma unroll
            for (int nf = 0; nf < 2; ++nf)
                bb[nf][kk] = *(const s16x8*)(&AB[cb][1][1][wcol + nf * 16 + l16][sw]);
        }
        stage(pB, 1, 0, T + 2);
        asm volatile("" ::: "memory");
        __builtin_amdgcn_s_barrier();
        asm volatile("" ::: "memory");
        __builtin_amdgcn_s_setprio(1);
#pragma unroll
        for (int kk = 0; kk < 2; ++kk)
#pragma unroll
            for (int mf = 0; mf < 4; ++mf)
#pragma unroll
                for (int nf = 0; nf < 2; ++nf)
                    acc[3][mf][nf] = __builtin_amdgcn_mfma_f32_16x16x32_bf16(
                        af[mf][kk], bb[nf][kk], acc[3][mf][nf], 0, 0, 0);
        __builtin_amdgcn_s_setprio(0);
        if (T < nt - 2) asm volatile("s_waitcnt vmcnt(4)" ::: "memory");
        else if (T == nt - 2) asm volatile("s_waitcnt vmcnt(0)" ::: "memory");
        asm volatile("" ::: "memory");
        __builtin_amdgcn_s_barrier();
        asm volatile("" ::: "memory");
    }

    void* Oo = P.O[z];
#pragma unroll
    for (int q = 0; q < 4; ++q) {
        const int qm = q >> 1, qn = q & 1;
#pragma unroll
        for (int mf = 0; mf < 4; ++mf) {
#pragma unroll
            for (int nf = 0; nf < 2; ++nf) {
#pragma unroll
                for (int rr = 0; rr < 4; ++rr) {
                    int grow = (int)bm * 256 + qm * 128 + wrow + mf * 16 + lh * 4 + rr;
                    int gcol = (int)bn * 256 + qn * 128 + wcol + nf * 16 + l16;
                    size_t idx = (size_t)grow * Nn + gcol;
                    float v = acc[q][mf][nf][rr];
                    if constexpr (EPI == 0) ((u16*)Oo)[idx] = f2bf(v);
                    else ((float*)Oo)[idx] = v;
                }
            }
        }
    }
}

// ======================= 2-phase 128x128 GEMM (bf16 both sides) ==============
// EPI 1: f32 store   4: atomicAdd f32 (split-K residual)
struct GemmB2 {
    const u16* A[5];
    const u16* B[5];
    void* O[5];
    int mrows[5];
    int koff[5];
};

template <int EPI>
__global__ __launch_bounds__(256) void k_gemm2(GemmB2 P, int Nn, int Kstep, int Kfull) {
    int z = blockIdx.z;
    size_t bm = blockIdx.y, bn = blockIdx.x;
    if ((int)(bm * 128) >= P.mrows[z]) return;
    const u16* A = P.A[z];
    const u16* Bw = P.B[z];
    int koff = P.koff[z];
    __shared__ __align__(16) u16 As[128 * 64];
    __shared__ __align__(16) u16 Bs[128 * 64];
    int tid = threadIdx.x;
    int lane = tid & 63, wid = tid >> 6;
    int l16 = lane & 15, lh = lane >> 4;
    int wm = (wid >> 1) * 64, wn = (wid & 1) * 64;

    const u16 *pA[4], *pB[4];
    int ldso[4];
#pragma unroll
    for (int i = 0; i < 4; ++i) {
        int c = tid + 256 * i;
        int r = c >> 3, s = c & 7;
        int ssw = (s ^ (r & 7)) * 8;  // inverse-swizzled source group
        pA[i] = A + (size_t)(bm * 128 + r) * Kfull + koff + ssw;
        pB[i] = Bw + (size_t)(bn * 128 + r) * Kfull + koff + ssw;
        ldso[i] = c * 8;  // linear dest
    }

    f32x4 acc[4][4];
#pragma unroll
    for (int i = 0; i < 4; ++i)
#pragma unroll
        for (int j = 0; j < 4; ++j)
#pragma unroll
            for (int e = 0; e < 4; ++e) acc[i][j][e] = 0.f;

    int nt = Kstep >> 6;
    for (int t = 0; t < nt; ++t) {
        int k0 = t << 6;
#pragma unroll
        for (int i = 0; i < 4; ++i) gload_lds16(pA[i] + k0, &As[ldso[i]]);
#pragma unroll
        for (int i = 0; i < 4; ++i) gload_lds16(pB[i] + k0, &Bs[ldso[i]]);
        __syncthreads();
#pragma unroll
        for (int kk = 0; kk < 2; ++kk) {
            int sidx = kk * 4 + lh;
            int sw = (sidx ^ (l16 & 7)) * 8;
            s16x8 af[4], bf4[4];
#pragma unroll
            for (int mi = 0; mi < 4; ++mi)
                af[mi] = *(const s16x8*)(&As[(wm + mi * 16 + l16) * 64 + sw]);
#pragma unroll
            for (int ni = 0; ni < 4; ++ni)
                bf4[ni] = *(const s16x8*)(&Bs[(wn + ni * 16 + l16) * 64 + sw]);
#pragma unroll
            for (int mi = 0; mi < 4; ++mi)
#pragma unroll
                for (int ni = 0; ni < 4; ++ni)
                    acc[mi][ni] = __builtin_amdgcn_mfma_f32_16x16x32_bf16(
                        af[mi], bf4[ni], acc[mi][ni], 0, 0, 0);
        }
        __syncthreads();
    }

    void* Oo = P.O[z];
#pragma unroll
    for (int mi = 0; mi < 4; ++mi) {
#pragma unroll
        for (int ni = 0; ni < 4; ++ni) {
#pragma unroll
            for (int r = 0; r < 4; ++r) {
                int grow = (int)bm * 128 + wm + mi * 16 + lh * 4 + r;
                int gcol = (int)bn * 128 + wn + ni * 16 + l16;
                size_t idx = (size_t)grow * Nn + gcol;
                float v = acc[mi][ni][r];
                if constexpr (EPI == 1) ((float*)Oo)[idx] = v;
                else atomicAdd((float*)Oo + idx, v);
            }
        }
    }
}

// ---------------- flash attention: 1 wave per (16 q-rows, head) -------------
__global__ __launch_bounds__(64) void k_attn(const u16* __restrict__ Qb,
                                             const u16* __restrict__ Kb,
                                             const u16* __restrict__ VT,
                                             u16* __restrict__ Ob) {
    int qt = blockIdx.x, hd = blockIdx.y;
    int lane = threadIdx.x, l16 = lane & 15, lh = lane >> 4;
    __shared__ __align__(16) float Pl[16 * 36];

    s16x8 qf[4];
#pragma unroll
    for (int c = 0; c < 4; ++c)
        qf[c] = *(const s16x8*)(Qb + (size_t)(qt * 16 + l16) * D_ + hd * DH + c * 32 + lh * 8);

    f32x4 o[8];
#pragma unroll
    for (int dc = 0; dc < 8; ++dc)
#pragma unroll
        for (int e = 0; e < 4; ++e) o[dc][e] = 0.f;
    float m[4], lsum[4];
#pragma unroll
    for (int r = 0; r < 4; ++r) { m[r] = -1e30f; lsum[r] = 0.f; }

    const float scale = 0.08838834764831845f;
    int qbase = M_ + qt * 16;
    int nkb = (M_ + qt * 16 + 16 + 31) >> 5;

    for (int kb = 0; kb < nkb; ++kb) {
        f32x4 s0, s1;
#pragma unroll
        for (int e = 0; e < 4; ++e) { s0[e] = 0.f; s1[e] = 0.f; }
#pragma unroll
        for (int c = 0; c < 4; ++c) {
            s16x8 kf0 = *(const s16x8*)(Kb + (size_t)(kb * 32 + l16) * D_ + hd * DH + c * 32 + lh * 8);
            s16x8 kf1 = *(const s16x8*)(Kb + (size_t)(kb * 32 + 16 + l16) * D_ + hd * DH + c * 32 + lh * 8);
            s0 = __builtin_amdgcn_mfma_f32_16x16x32_bf16(qf[c], kf0, s0, 0, 0, 0);
            s1 = __builtin_amdgcn_mfma_f32_16x16x32_bf16(qf[c], kf1, s1, 0, 0, 0);
        }
        int kp0 = kb * 32 + l16, kp1 = kp0 + 16;
        float pm[4];
#pragma unroll
        for (int r = 0; r < 4; ++r) {
            int qp = qbase + lh * 4 + r;
            float v0 = s0[r] * scale; if (kp0 > qp) v0 = -1e30f;
            float v1 = s1[r] * scale; if (kp1 > qp) v1 = -1e30f;
            s0[r] = v0; s1[r] = v1;
            pm[r] = fmaxf(v0, v1);
        }
#pragma unroll
        for (int r = 0; r < 4; ++r) {
#pragma unroll
            for (int off = 8; off; off >>= 1) pm[r] = fmaxf(pm[r], __shfl_xor(pm[r], off));
        }
        float alpha[4];
#pragma unroll
        for (int r = 0; r < 4; ++r) {
            float mn = fmaxf(m[r], pm[r]);
            alpha[r] = __expf(m[r] - mn);
            m[r] = mn;
            float p0 = __expf(s0[r] - mn), p1 = __expf(s1[r] - mn);
            s0[r] = p0; s1[r] = p1;
            float t = p0 + p1;
#pragma unroll
            for (int off = 8; off; off >>= 1) t += __shfl_xor(t, off);
            lsum[r] = lsum[r] * alpha[r] + t;
        }
#pragma unroll
        for (int r = 0; r < 4; ++r) {
            Pl[(lh * 4 + r) * 36 + l16] = s0[r];
            Pl[(lh * 4 + r) * 36 + 16 + l16] = s1[r];
        }
        __syncthreads();
        s16x8 pf;
        {
            const f32x4* pp = (const f32x4*)(Pl + l16 * 36 + lh * 8);
            f32x4 a = pp[0], b = pp[1];
            pf[0] = (short)f2bf(a[0]); pf[1] = (short)f2bf(a[1]);
            pf[2] = (short)f2bf(a[2]); pf[3] = (short)f2bf(a[3]);
            pf[4] = (short)f2bf(b[0]); pf[5] = (short)f2bf(b[1]);
            pf[6] = (short)f2bf(b[2]); pf[7] = (short)f2bf(b[3]);
        }
        __syncthreads();
#pragma unroll
        for (int dc = 0; dc < 8; ++dc) {
#pragma unroll
            for (int r = 0; r < 4; ++r) o[dc][r] *= alpha[r];
        }
#pragma unroll
        for (int dc = 0; dc < 8; ++dc) {
            s16x8 vf = *(const s16x8*)(VT + (size_t)(hd * DH + dc * 16 + l16) * KV_ + kb * 32 + lh * 8);
            o[dc] = __builtin_amdgcn_mfma_f32_16x16x32_bf16(pf, vf, o[dc], 0, 0, 0);
        }
    }
#pragma unroll
    for (int dc = 0; dc < 8; ++dc) {
#pragma unroll
        for (int r = 0; r < 4; ++r) {
            float val = o[dc][r] / lsum[r];
            Ob[(size_t)(qt * 16 + lh * 4 + r) * D_ + hd * DH + dc * 16 + l16] = f2bf(val);
        }
    }
}

// ---------------- launch ----------------------------------------------------
extern "C" void kernel_launch(void* const* d_in, const int* in_sizes, int n_in,
                              void* d_out, int out_size, void* d_ws, size_t ws_size,
                              hipStream_t stream) {
    const int* ids = (const int*)d_in[0];
    const float* memory = (const float*)d_in[1];
    const float* embed = (const float*)d_in[2];
    const float* Wq = (const float*)d_in[3];
    const float* Wk = (const float*)d_in[4];
    const float* Wv = (const float*)d_in[5];
    const float* Wo = (const float*)d_in[6];
    const float* Wg = (const float*)d_in[7];
    const float* Wu = (const float*)d_in[8];
    const float* Wd = (const float*)d_in[9];
    const float* Wmk = (const float*)d_in[10];
    const float* Wmv = (const float*)d_in[11];
    const float* ln1 = (const float*)d_in[12];
    const float* ln2 = (const float*)d_in[13];
    const float* normw = (const float*)d_in[14];
    const float* lm = (const float*)d_in[15];

    char* ws = (char*)d_ws;
    float* h   = (float*)(ws + 0x0000000);   // 16.78 MB f32 [S][D]
    u16* xb    = (u16*)(ws + 0x1000000);     // 8.39 MB bf16 [S][D]
    float* tab = (float*)(ws + 0x1800000);   // 0.79 MB
    u16* memb  = (u16*)(ws + 0x1900000);     // 4.19 MB
    u16* Qb    = (u16*)(ws + 0x1E00000);     // 8.39 MB
    u16* Kb    = (u16*)(ws + 0x2600000);     // 12.58 MB [KV][D]
    u16* Vb    = (u16*)(ws + 0x3200000);     // 12.58 MB
    u16* VT    = (u16*)(ws + 0x3E00000);     // 12.58 MB [D][KV]
    u16* Ob    = (u16*)(ws + 0x4A00000);     // 8.39 MB
    // FFN overlays (Qb..Ob dead then):
    u16* Gb16  = (u16*)(ws + 0x1E00000);     // 16.78 MB bf16 [S][F]
    u16* Ub16  = (u16*)(ws + 0x2E00000);     // 16.78 MB bf16 [S][F]
    u16* tb    = (u16*)(ws + 0x3E00000);     // 16.78 MB bf16 [S][F]
    // bf16 weights (converted once per call):
    u16* Wqb  = (u16*)(ws + 0x07000000);
    u16* Wkb  = (u16*)(ws + 0x0B000000);
    u16* Wvb  = (u16*)(ws + 0x0F000000);
    u16* Wob  = (u16*)(ws + 0x13000000);
    u16* Wmkb = (u16*)(ws + 0x17000000);
    u16* Wmvb = (u16*)(ws + 0x1B000000);
    u16* Wgb  = (u16*)(ws + 0x1F000000);
    u16* Wub  = (u16*)(ws + 0x27000000);
    u16* Wdb  = (u16*)(ws + 0x2F000000);
    u16* lmb  = (u16*)(ws + 0x37000000);     // end 0x3B000000

    // ---- weight conversion (f32 -> bf16, RNE) ----
    const int nDD = L_ * D_ * D_ / 4, nFD = L_ * F_ * D_ / 4, nVD = V_ * D_ / 4;
    k_cvt<<<(nDD + 255) / 256, 256, 0, stream>>>(Wq, Wqb, nDD);
    k_cvt<<<(nDD + 255) / 256, 256, 0, stream>>>(Wk, Wkb, nDD);
    k_cvt<<<(nDD + 255) / 256, 256, 0, stream>>>(Wv, Wvb, nDD);
    k_cvt<<<(nDD + 255) / 256, 256, 0, stream>>>(Wo, Wob, nDD);
    k_cvt<<<(nDD + 255) / 256, 256, 0, stream>>>(Wmk, Wmkb, nDD);
    k_cvt<<<(nDD + 255) / 256, 256, 0, stream>>>(Wmv, Wmvb, nDD);
    k_cvt<<<(nFD + 255) / 256, 256, 0, stream>>>(Wg, Wgb, nFD);
    k_cvt<<<(nFD + 255) / 256, 256, 0, stream>>>(Wu, Wub, nFD);
    k_cvt<<<(nFD + 255) / 256, 256, 0, stream>>>(Wd, Wdb, nFD);
    k_cvt<<<(nVD + 255) / 256, 256, 0, stream>>>(lm, lmb, nVD);

    k_embed<<<S_, 256, 0, stream>>>(ids, embed, h);
    k_ropetab<<<KV_, 64, 0, stream>>>(tab);

    for (int l = 0; l < L_; ++l) {
        const size_t oDD = (size_t)l * D_ * D_;
        const size_t oFD = (size_t)l * F_ * D_;

        k_rms<<<S_, 256, 0, stream>>>(h, ln1 + l * D_, xb);
        k_cvt<<<(M_ * D_ / 4 + 255) / 256, 256, 0, stream>>>(
            memory + (size_t)l * M_ * D_, memb, M_ * D_ / 4);

        // QKV + memory-KV: 8-phase 256^2, 5 z-slices
        GemmB8 g1{};
        g1.A[0] = xb;   g1.B[0] = Wqb + oDD;  g1.O[0] = Qb;                    g1.mrows[0] = S_;
        g1.A[1] = xb;   g1.B[1] = Wkb + oDD;  g1.O[1] = Kb + (size_t)M_ * D_;  g1.mrows[1] = S_;
        g1.A[2] = xb;   g1.B[2] = Wvb + oDD;  g1.O[2] = Vb + (size_t)M_ * D_;  g1.mrows[2] = S_;
        g1.A[3] = memb; g1.B[3] = Wmkb + oDD; g1.O[3] = Kb;                    g1.mrows[3] = M_;
        g1.A[4] = memb; g1.B[4] = Wmvb + oDD; g1.O[4] = Vb;                    g1.mrows[4] = M_;
        k_gemm8<0><<<dim3(D_ / 256, S_ / 256, 5), 512, 0, stream>>>(g1, D_, D_);

        k_rope<<<S_, 256, 0, stream>>>(Qb, tab, M_);
        k_rope<<<KV_, 256, 0, stream>>>(Kb, tab, 0);
        k_transpose<<<dim3(D_ / 64, KV_ / 64), 256, 0, stream>>>(Vb, VT);
        k_attn<<<dim3(S_ / 16, H_), 64, 0, stream>>>(Qb, Kb, VT, Ob);

        // h += Ob @ Wo^T  (split-K=2, atomicAdd residual)
        GemmB2 g2{};
        g2.A[0] = Ob; g2.B[0] = Wob + oDD; g2.O[0] = h; g2.mrows[0] = S_; g2.koff[0] = 0;
        g2.A[1] = Ob; g2.B[1] = Wob + oDD; g2.O[1] = h; g2.mrows[1] = S_; g2.koff[1] = 2048;
        k_gemm2<4><<<dim3(D_ / 128, S_ / 128, 2), 256, 0, stream>>>(g2, D_, 2048, D_);

        // FFN
        k_rms<<<S_, 256, 0, stream>>>(h, ln2 + l * D_, xb);
        GemmB8 g3{};
        g3.A[0] = xb; g3.B[0] = Wgb + oFD; g3.O[0] = Gb16; g3.mrows[0] = S_;
        g3.A[1] = xb; g3.B[1] = Wub + oFD; g3.O[1] = Ub16; g3.mrows[1] = S_;
        k_gemm8<0><<<dim3(F_ / 256, S_ / 256, 2), 512, 0, stream>>>(g3, F_, D_);
        k_silu<<<(S_ * F_ / 8 + 255) / 256, 256, 0, stream>>>(Gb16, Ub16, tb, S_ * F_ / 8);
        GemmB2 g5{};
        g5.A[0] = tb; g5.B[0] = Wdb + oFD; g5.O[0] = h; g5.mrows[0] = S_; g5.koff[0] = 0;
        g5.A[1] = tb; g5.B[1] = Wdb + oFD; g5.O[1] = h; g5.mrows[1] = S_; g5.koff[1] = 4096;
        k_gemm2<4><<<dim3(D_ / 128, S_ / 128, 2), 256, 0, stream>>>(g5, D_, 4096, F_);
    }

    k_rms<<<S_, 256, 0, stream>>>(h, normw, xb);
    GemmB2 g6{};
    g6.A[0] = xb; g6.B[0] = lmb; g6.O[0] = (float*)d_out; g6.mrows[0] = S_; g6.koff[0] = 0;
    k_gemm2<1><<<dim3(V_ / 128, S_ / 128, 1), 256, 0, stream>>>(g6, V_, D_, D_);
}